// Round 1
// 376.320 us; speedup vs baseline: 1.0620x; 1.0620x over previous
//
#include <hip/hip_runtime.h>
#include <hip/hip_bf16.h>
#include <stdint.h>

typedef __attribute__((ext_vector_type(8))) short short8;
typedef __attribute__((ext_vector_type(4))) short short4v;
typedef __attribute__((ext_vector_type(4))) float f32x4;

__device__ inline unsigned short f2bf(float f) {
    union { float f; uint32_t u; } v; v.f = f;
    uint32_t u = v.u;
    uint32_t r = (u + 0x7FFFu + ((u >> 16) & 1u)) >> 16;   // RNE
    return (unsigned short)r;
}

__device__ inline short4v pk4(float4 a) {
    short4v r;
    r[0] = (short)f2bf(a.x); r[1] = (short)f2bf(a.y);
    r[2] = (short)f2bf(a.z); r[3] = (short)f2bf(a.w);
    return r;
}

// ---------------- Router kernel 1: partial GEMM  h_pre = g_in @ W1 -------------
// grid (16, 64). Index remap: bg = lin bits[3:4] so the 4 blocks sharing one
// W1 [64k x 512j] slice land on the SAME XCD (lin%8 equal) -> slice is an L2
// hit after first touch instead of 4x HBM/L3 fetches. Mapping is bijective:
// grp uses lin bits {0,1,2,5..9}, bg uses {3,4}.
__global__ __launch_bounds__(256) void router1(const float* __restrict__ DKP,
                                               const float* __restrict__ W1,
                                               float* __restrict__ part) {
    __shared__ float gin[16 * 64];
    const int t  = threadIdx.x;
    const int lin = blockIdx.x + 16 * blockIdx.y;
    const int bg  = (lin >> 3) & 3;
    const int grp = (lin & 7) | ((lin >> 5) << 3);   // 0..255
    const int jc  = grp & 3;
    const int ks  = grp >> 2;
    const int k0 = ks * 64;
    {   // stage g_in chunk [16 b][64 k]
        const int b = t >> 4, q = t & 15;
        *(float4*)(gin + b * 64 + q * 4) =
            *(const float4*)(DKP + (size_t)(bg * 16 + b) * 4096 + k0 + q * 4);
    }
    __syncthreads();
    const int ja = jc * 512 + t, jb = ja + 256;
    float accA[16], accB[16];
    #pragma unroll
    for (int b = 0; b < 16; ++b) { accA[b] = 0.f; accB[b] = 0.f; }
    #pragma unroll 1
    for (int oct = 0; oct < 8; ++oct) {
        const int kk = oct * 8;
        float wa[8], wb[8];
        #pragma unroll
        for (int i = 0; i < 8; ++i) {
            const float* wr = W1 + (size_t)(k0 + kk + i) * 2048;
            wa[i] = wr[ja]; wb[i] = wr[jb];
        }
        #pragma unroll
        for (int b = 0; b < 16; ++b) {
            float4 g0 = *(const float4*)(gin + b * 64 + kk);
            float4 g1 = *(const float4*)(gin + b * 64 + kk + 4);
            accA[b] += g0.x*wa[0] + g0.y*wa[1] + g0.z*wa[2] + g0.w*wa[3]
                     + g1.x*wa[4] + g1.y*wa[5] + g1.z*wa[6] + g1.w*wa[7];
            accB[b] += g0.x*wb[0] + g0.y*wb[1] + g0.z*wb[2] + g0.w*wb[3]
                     + g1.x*wb[4] + g1.y*wb[5] + g1.z*wb[6] + g1.w*wb[7];
        }
    }
    #pragma unroll 1
    for (int b = 0; b < 16; ++b) {
        const size_t row = (size_t)(ks * 64 + bg * 16 + b) * 2048;
        part[row + ja] = accA[b];
        part[row + jb] = accB[b];
    }
}

// ---------------- Router kernel 2: reduce splits + cycle-number col + bias + GELU
__global__ __launch_bounds__(256) void router2(const float* __restrict__ part,
                                               const float* __restrict__ cyc,
                                               const float* __restrict__ W1,
                                               const float* __restrict__ b1,
                                               float* __restrict__ h) {
    const int idx = blockIdx.x * 256 + threadIdx.x;   // idx = b*2048 + j
    const int j = idx & 2047, b = idx >> 11;
    float s = 0.f;
    #pragma unroll 8
    for (int t = 0; t < 64; ++t)
        s += part[((size_t)t * 64 + b) * 2048 + j];
    s += cyc[b] * W1[(size_t)4096 * 2048 + j] + b1[j];
    // jax.nn.gelu default (tanh approximation)
    const float u  = s + 0.044715f * s * s * s;
    const float th = tanhf(0.7978845608028654f * u);
    h[idx] = 0.5f * s * (1.0f + th);
}

// ---------------- Router kernel 3: logits, top-2, softmax, renorm gates -------
__global__ __launch_bounds__(256) void router3(const float* __restrict__ h,
                                               const float* __restrict__ W2,
                                               const float* __restrict__ b2,
                                               float4* __restrict__ gates) {
    __shared__ float red[256 * 8];
    __shared__ float lg[8];
    const int b = blockIdx.x, t = threadIdx.x;
    float acc[8];
    #pragma unroll
    for (int e = 0; e < 8; ++e) acc[e] = 0.f;
    for (int k = t; k < 2048; k += 256) {
        const float hv = h[(size_t)b * 2048 + k];
        const float* w = W2 + (size_t)k * 8;
        #pragma unroll
        for (int e = 0; e < 8; ++e) acc[e] += hv * w[e];
    }
    #pragma unroll
    for (int e = 0; e < 8; ++e) red[t * 8 + e] = acc[e];
    __syncthreads();
    if (t < 8) {
        float s = 0.f;
        for (int r = 0; r < 256; ++r) s += red[r * 8 + t];
        lg[t] = s + b2[t];
    }
    __syncthreads();
    if (t == 0) {
        float l[8];
        #pragma unroll
        for (int e = 0; e < 8; ++e) l[e] = lg[e];
        int e0 = 0;
        #pragma unroll
        for (int e = 1; e < 8; ++e) if (l[e] > l[e0]) e0 = e;
        int e1 = (e0 == 0) ? 1 : 0;
        #pragma unroll
        for (int e = 0; e < 8; ++e) if (e != e0 && l[e] > l[e1]) e1 = e;
        const float m = l[e0];
        float p[8], Z = 0.f;
        #pragma unroll
        for (int e = 0; e < 8; ++e) { p[e] = expf(l[e] - m); Z += p[e]; }
        const float pe0 = p[e0] / Z, pe1 = p[e1] / Z;
        const float s2 = pe0 + pe1 + 1e-9f;
        gates[b] = make_float4(__int_as_float(e0), __int_as_float(e1), pe0 / s2, pe1 / s2);
    }
}

// ---------------- Combine weights: Wcomb^T[b][d][i] = (genW + g0*We0 + g1*We1)^T, bf16, K-pad to 928
__global__ __launch_bounds__(256) void combine_w(const float* __restrict__ genW,
                                                 const float* __restrict__ expW,
                                                 const float4* __restrict__ gates,
                                                 unsigned short* __restrict__ wc) {
    __shared__ unsigned short T[64 * 72];   // [d_loc][i_loc], stride 72 for aligned b128 row reads
    const int b  = blockIdx.z;
    const int i0 = blockIdx.y * 64;
    const int d0 = blockIdx.x * 64;
    const float4 gt = gates[b];
    const int e0 = __float_as_int(gt.x), e1 = __float_as_int(gt.y);
    const float g0 = gt.z, g1 = gt.w;
    const float* W0 = expW + (size_t)e0 * 900 * 512;
    const float* W1e = expW + (size_t)e1 * 900 * 512;
    const int t = threadIdx.x;
    {
        const int il = t >> 2, c = t & 3;
        const int i = i0 + il;
        const bool valid = (i < 900);
        const size_t rowoff = (size_t)i * 512 + d0 + c * 16;
        #pragma unroll
        for (int s = 0; s < 4; ++s) {
            float4 g  = valid ? *(const float4*)(genW + rowoff + 4 * s) : make_float4(0,0,0,0);
            float4 w0 = valid ? *(const float4*)(W0   + rowoff + 4 * s) : make_float4(0,0,0,0);
            float4 w1 = valid ? *(const float4*)(W1e  + rowoff + 4 * s) : make_float4(0,0,0,0);
            const int dl = c * 16 + 4 * s;
            T[(dl + 0) * 72 + il] = f2bf(g.x + g0 * w0.x + g1 * w1.x);
            T[(dl + 1) * 72 + il] = f2bf(g.y + g0 * w0.y + g1 * w1.y);
            T[(dl + 2) * 72 + il] = f2bf(g.z + g0 * w0.z + g1 * w1.z);
            T[(dl + 3) * 72 + il] = f2bf(g.w + g0 * w0.w + g1 * w1.w);
        }
    }
    __syncthreads();
    {
        const int dl = t >> 2, seg = t & 3;
        const int ic = seg * 16;
        if (i0 + ic < 928) {
            short8 v0 = *(const short8*)&T[dl * 72 + ic];
            short8 v1 = *(const short8*)&T[dl * 72 + ic + 8];
            unsigned short* dst = wc + (size_t)b * 512 * 928 + (size_t)(d0 + dl) * 928 + i0 + ic;
            *(short8*)dst = v0;
            *((short8*)dst + 1) = v1;
        }
    }
}

// ---------------- Main fused batched GEMM: out[b] = x[b] @ Wcomb_b + bias ------
// Tile 64m x 512n (FULL d) per block, 512 threads = 8 waves (each wave 64x64),
// BK=32, 16x16x32 bf16 MFMA. grid (64 b, 8 m): linear%8 = b%8 -> all of battery
// b's blocks land on one XCD (wcomb_b L2-resident); x fetched exactly once.
//
// R2: double-buffered LDS pipeline (T3-min 2-phase). Per k-step:
//   issue A global float4 (t+1)  -> regs              (issued FIRST: pack waits vmcnt(4))
//   issue B global_load_lds (t+1) -> Bs[buf^1]        (4 per wave, in flight across compute)
//   ds_read frags + 16 MFMA from buf                  (loads hide under this)
//   pack A regs -> ds_write As[buf^1]                 (T14 split: x latency hidden under MFMA)
//   __syncthreads()  (its vmcnt(0) drain now waits on loads that had the whole
//                     compute phase in flight — the R1 version drained BEFORE compute)
// Loop hand-unrolled x2 so buffer indices are compile-time constants.
// LDS 2*(5120+32768)=75776 B -> still exactly 2 blocks/CU.
__global__ __launch_bounds__(512, 4) void moe_gemm(const float* __restrict__ x,
                                                   const unsigned short* __restrict__ wc,
                                                   const float4* __restrict__ gates,
                                                   const float* __restrict__ eb,
                                                   const float* __restrict__ genb,
                                                   float* __restrict__ out) {
    __shared__ unsigned short As[2][64 * 40];    // [m][k] bf16, padded stride 40
    __shared__ unsigned short Bs[2][512 * 32];   // [n][k] bf16, rows 64B contiguous, slots swizzled
    const int b  = blockIdx.x;
    const int m0 = blockIdx.y * 64;
    const int t = threadIdx.x, lane = t & 63, wid = t >> 6;
    const float4 gt = gates[b];
    const int e0 = __float_as_int(gt.x), e1 = __float_as_int(gt.y);
    const float g0 = gt.z, g1 = gt.w;
    const float* xb = x + (size_t)b * 512 * 900;
    const unsigned short* wcb = wc + (size_t)b * 512 * 928;
    f32x4 acc[4][4];
    #pragma unroll
    for (int mi = 0; mi < 4; ++mi)
        #pragma unroll
        for (int ni = 0; ni < 4; ++ni)
            acc[mi][ni] = (f32x4){0.f, 0.f, 0.f, 0.f};

    // A staging: thread -> (row = t>>3, 4 floats at (t&7)*4)
    const int arow  = t >> 3;
    const int akoff = (t & 7) * 4;
    const float* xrow = xb + (size_t)(m0 + arow) * 900 + akoff;
    // B staging: lane -> row u=lane>>2 within 16-row chunk; slot=lane&3 holds
    // global seg = slot ^ ((n>>1)&3) = slot ^ ((lane>>3)&3)
    const int bseg = (lane & 3) ^ ((lane >> 3) & 3);
    const int burow = lane >> 2;

    const int wn = wid * 64;
    const int lm = lane & 15, lq = lane >> 4;

    // ---- pipeline helpers (all inlined with constant buf after unroll) ----
    auto loadA = [&](int kt) -> float4 {
        if (kt < 28) return *(const float4*)(xrow + kt * 32);
        // tail k-step: k0=896, only akoff==0 lanes have k<900 (896..899)
        float4 z = make_float4(0.f, 0.f, 0.f, 0.f);
        if (akoff == 0) z = *(const float4*)(xrow + 896);
        return z;
    };
    auto stageB = [&](int buf, int kt) {
        const int k0 = kt * 32;
        #pragma unroll
        for (int r = 0; r < 4; ++r) {
            const int chunk = wid * 4 + r;
            const int n = chunk * 16 + burow;
            const unsigned short* gsrc = wcb + (size_t)n * 928 + k0 + bseg * 8;
            unsigned short* ldst = &Bs[buf][chunk * 512];
            __builtin_amdgcn_global_load_lds(
                (const __attribute__((address_space(1))) unsigned int*)gsrc,
                (__attribute__((address_space(3))) unsigned int*)ldst, 16, 0, 0);
        }
    };
    auto packA = [&](int buf, float4 f) {
        *(short4v*)&As[buf][arow * 40 + akoff] = pk4(f);
    };
    auto compute = [&](int buf) {
        short8 af[4], bfr[4];
        #pragma unroll
        for (int mi = 0; mi < 4; ++mi)
            af[mi] = *(const short8*)&As[buf][(mi * 16 + lm) * 40 + lq * 8];
        #pragma unroll
        for (int ni = 0; ni < 4; ++ni) {
            const int n = wn + ni * 16 + lm;
            const int slot = lq ^ ((lm >> 1) & 3);
            bfr[ni] = *(const short8*)&Bs[buf][n * 32 + slot * 8];
        }
        #pragma unroll
        for (int mi = 0; mi < 4; ++mi)
            #pragma unroll
            for (int ni = 0; ni < 4; ++ni)
                acc[mi][ni] = __builtin_amdgcn_mfma_f32_16x16x32_bf16(
                    af[mi], bfr[ni], acc[mi][ni], 0, 0, 0);
    };

    // ---- prologue: stage kt=0 into buf 0
    {
        float4 a0 = loadA(0);
        stageB(0, 0);
        packA(0, a0);
        __syncthreads();
    }
    // ---- main loop: 28 steps staging ahead, hand-unrolled x2 (14 pairs)
    #pragma unroll 1
    for (int kt2 = 0; kt2 < 14; ++kt2) {
        {
            float4 an = loadA(2 * kt2 + 1);
            stageB(1, 2 * kt2 + 1);
            compute(0);
            packA(1, an);
            __syncthreads();
        }
        {
            float4 an = loadA(2 * kt2 + 2);
            stageB(0, 2 * kt2 + 2);
            compute(1);
            packA(0, an);
            __syncthreads();
        }
    }
    // ---- epilogue step: compute kt=28 from buf 0 (no further staging)
    compute(0);

    // ---- Epilogue: add gen_b + g0*eb[e0] + g1*eb[e1], store f32
    #pragma unroll
    for (int ni = 0; ni < 4; ++ni) {
        const int col = wn + ni * 16 + lm;
        const float bias = genb[col] + g0 * eb[e0 * 512 + col] + g1 * eb[e1 * 512 + col];
        #pragma unroll
        for (int mi = 0; mi < 4; ++mi) {
            const int row = m0 + mi * 16 + lq * 4;
            #pragma unroll
            for (int r = 0; r < 4; ++r)
                out[((size_t)b * 512 + row + r) * 512 + col] = acc[mi][ni][r] + bias;
        }
    }
}

extern "C" void kernel_launch(void* const* d_in, const int* in_sizes, int n_in,
                              void* d_out, int out_size, void* d_ws, size_t ws_size,
                              hipStream_t stream) {
    const float* x    = (const float*)d_in[0];   // [64][512][900]
    const float* cyc  = (const float*)d_in[1];   // [64][1]
    const float* dkp  = (const float*)d_in[2];   // [64][4096]
    const float* gW1  = (const float*)d_in[3];   // [4097][2048]
    const float* gb1  = (const float*)d_in[4];   // [2048]
    const float* gW2  = (const float*)d_in[5];   // [2048][8]
    const float* gb2  = (const float*)d_in[6];   // [8]
    const float* eW   = (const float*)d_in[7];   // [8][900][512]
    const float* eb   = (const float*)d_in[8];   // [8][512]
    const float* genW = (const float*)d_in[9];   // [900][512]
    const float* genb = (const float*)d_in[10];  // [512]
    float* out = (float*)d_out;                  // [64][512][512] f32

    char* ws = (char*)d_ws;
    // ws layout: [0, 60817408): Wcomb bf16 [64][512][928]; partials (33.5MB) alias
    // this region (dead before combine_w runs). Then h (512KB), gates (1KB).
    unsigned short* wcomb = (unsigned short*)ws;
    float* part  = (float*)ws;                          // [64][64][2048] f32
    float* h     = (float*)(ws + 60817408);             // [64][2048] f32
    float4* gts  = (float4*)(ws + 60817408 + 524288);   // [64] {e0,e1,g0,g1}

    router1<<<dim3(16, 64), 256, 0, stream>>>(dkp, gW1, part);
    router2<<<512, 256, 0, stream>>>(part, cyc, gW1, gb1, h);
    router3<<<64, 256, 0, stream>>>(h, gW2, gb2, gts);
    combine_w<<<dim3(8, 15, 64), 256, 0, stream>>>(genW, eW, gts, wcomb);
    moe_gemm<<<dim3(64, 8), 512, 0, stream>>>(x, wcomb, gts, eb, genb, out);
}

// Round 2
// 363.456 us; speedup vs baseline: 1.0996x; 1.0354x over previous
//
#include <hip/hip_runtime.h>
#include <hip/hip_bf16.h>
#include <stdint.h>

typedef __attribute__((ext_vector_type(8))) short short8;
typedef __attribute__((ext_vector_type(4))) short short4v;
typedef __attribute__((ext_vector_type(4))) float f32x4;

__device__ inline unsigned short f2bf(float f) {
    union { float f; uint32_t u; } v; v.f = f;
    uint32_t u = v.u;
    uint32_t r = (u + 0x7FFFu + ((u >> 16) & 1u)) >> 16;   // RNE
    return (unsigned short)r;
}

__device__ inline short4v pk4(float4 a) {
    short4v r;
    r[0] = (short)f2bf(a.x); r[1] = (short)f2bf(a.y);
    r[2] = (short)f2bf(a.z); r[3] = (short)f2bf(a.w);
    return r;
}

// ---------------- Router kernel 1: partial GEMM  h_pre = g_in @ W1 -------------
// R2: k-split 16 (was 64) -> partials 8.4 MB (was 33.5); j-split 8 -> 512 blocks
// (2/CU). XCD grouping: lin%8 = jc (bg-independent) so the 4 bg-siblings sharing
// a W1 [256k x 256j] slice land on one XCD -> L2 hit after first touch.
// Bits: [0:2]=jc, [3:4]=bg, [5:8]=ks. Bijective.
__global__ __launch_bounds__(256) void router1(const float* __restrict__ DKP,
                                               const float* __restrict__ W1,
                                               float* __restrict__ part) {
    __shared__ float gin[16 * 256];   // 16 KB
    const int t   = threadIdx.x;
    const int lin = blockIdx.x + 16 * blockIdx.y;   // grid (16,32) -> 0..511
    const int jc  = lin & 7;
    const int bg  = (lin >> 3) & 3;
    const int ks  = lin >> 5;                        // 0..15
    const int k0  = ks * 256;
    {   // stage g_in chunk [16 b][256 k]
        const int b = t >> 4, q = t & 15;
        #pragma unroll
        for (int s = 0; s < 4; ++s)
            *(float4*)(gin + b * 256 + q * 16 + s * 4) =
                *(const float4*)(DKP + (size_t)(bg * 16 + b) * 4096 + k0 + q * 16 + s * 4);
    }
    __syncthreads();
    const int ja = jc * 256 + t;
    float accA[16];
    #pragma unroll
    for (int b = 0; b < 16; ++b) accA[b] = 0.f;
    #pragma unroll 1
    for (int oct = 0; oct < 32; ++oct) {
        const int kk = oct * 8;
        float wa[8];
        #pragma unroll
        for (int i = 0; i < 8; ++i)
            wa[i] = W1[(size_t)(k0 + kk + i) * 2048 + ja];
        #pragma unroll
        for (int b = 0; b < 16; ++b) {
            float4 g0 = *(const float4*)(gin + b * 256 + kk);
            float4 g1 = *(const float4*)(gin + b * 256 + kk + 4);
            accA[b] += g0.x*wa[0] + g0.y*wa[1] + g0.z*wa[2] + g0.w*wa[3]
                     + g1.x*wa[4] + g1.y*wa[5] + g1.z*wa[6] + g1.w*wa[7];
        }
    }
    #pragma unroll 1
    for (int b = 0; b < 16; ++b)
        part[((size_t)(ks * 64 + bg * 16 + b)) * 2048 + ja] = accA[b];
}

// ---------------- Router 2+3 fused: reduce splits + GELU + logits + top-2 gates
__global__ __launch_bounds__(256) void router23(const float* __restrict__ part,
                                                const float* __restrict__ cyc,
                                                const float* __restrict__ W1,
                                                const float* __restrict__ b1,
                                                const float* __restrict__ W2,
                                                const float* __restrict__ b2,
                                                float4* __restrict__ gates) {
    __shared__ float red[256 * 8];
    __shared__ float lg[8];
    const int b = blockIdx.x, t = threadIdx.x;
    float acc[8];
    #pragma unroll
    for (int e = 0; e < 8; ++e) acc[e] = 0.f;
    #pragma unroll 1
    for (int jj = 0; jj < 8; ++jj) {
        const int j = jj * 256 + t;
        float s = 0.f;
        #pragma unroll
        for (int tt = 0; tt < 16; ++tt)
            s += part[((size_t)tt * 64 + b) * 2048 + j];
        s += cyc[b] * W1[(size_t)4096 * 2048 + j] + b1[j];
        // jax.nn.gelu default (tanh approximation)
        const float u  = s + 0.044715f * s * s * s;
        const float th = tanhf(0.7978845608028654f * u);
        const float hv = 0.5f * s * (1.0f + th);
        const float* w = W2 + (size_t)j * 8;
        #pragma unroll
        for (int e = 0; e < 8; ++e) acc[e] += hv * w[e];
    }
    #pragma unroll
    for (int e = 0; e < 8; ++e) red[t * 8 + e] = acc[e];
    __syncthreads();
    if (t < 8) {
        float s = 0.f;
        for (int r = 0; r < 256; ++r) s += red[r * 8 + t];
        lg[t] = s + b2[t];
    }
    __syncthreads();
    if (t == 0) {
        float l[8];
        #pragma unroll
        for (int e = 0; e < 8; ++e) l[e] = lg[e];
        int e0 = 0;
        #pragma unroll
        for (int e = 1; e < 8; ++e) if (l[e] > l[e0]) e0 = e;
        int e1 = (e0 == 0) ? 1 : 0;
        #pragma unroll
        for (int e = 0; e < 8; ++e) if (e != e0 && l[e] > l[e1]) e1 = e;
        const float m = l[e0];
        float p[8], Z = 0.f;
        #pragma unroll
        for (int e = 0; e < 8; ++e) { p[e] = expf(l[e] - m); Z += p[e]; }
        const float pe0 = p[e0] / Z, pe1 = p[e1] / Z;
        const float s2 = pe0 + pe1 + 1e-9f;
        gates[b] = make_float4(__int_as_float(e0), __int_as_float(e1), pe0 / s2, pe1 / s2);
    }
}

// ---------------- Combine weights: wc[b][d][i] = (genW + g0*We0 + g1*We1)^T bf16
// R2 rewrite: grid (16 d-tiles, 29 i-tiles) of [32i x 32d]; stage genW + ALL 8
// expert tiles transposed in LDS ONCE (9 x 4.5 KB = 41.5 KB), then loop the 64
// batteries in-block. Read traffic: 353 MB (per-battery re-reads, L3) -> 17 MB.
// Writes unchanged (61 MB HBM). i>=900 zero-padded (29*32 = 928 exactly).
__global__ __launch_bounds__(256) void combine_w(const float* __restrict__ genW,
                                                 const float* __restrict__ expW,
                                                 const float4* __restrict__ gates,
                                                 unsigned short* __restrict__ wc) {
    __shared__ float T[9][32 * 36];   // [src][d_loc][i_loc], pad 36 (rows 144B, 16B-aligned)
    __shared__ float4 gsh[64];
    const int t  = threadIdx.x;
    const int d0 = blockIdx.x * 32;
    const int i0 = blockIdx.y * 32;
    if (t < 64) gsh[t] = gates[t];
    {
        const int il = t >> 3, d4 = (t & 7) * 4;
        const int i = i0 + il;
        const bool valid = (i < 900);
        const size_t off = (size_t)i * 512 + d0 + d4;
        #pragma unroll
        for (int s = 0; s < 9; ++s) {
            const float* src = (s == 0) ? genW : (expW + (size_t)(s - 1) * 900 * 512);
            float4 v = valid ? *(const float4*)(src + off) : make_float4(0, 0, 0, 0);
            float* Td = &T[s][0];
            Td[(d4 + 0) * 36 + il] = v.x;
            Td[(d4 + 1) * 36 + il] = v.y;
            Td[(d4 + 2) * 36 + il] = v.z;
            Td[(d4 + 3) * 36 + il] = v.w;
        }
    }
    __syncthreads();
    const int dl = t >> 3, sg = t & 7;                 // d-row, i-segment (4 i each)
    const int fo = dl * 36 + sg * 4;
    unsigned short* wrow = wc + (size_t)(d0 + dl) * 928 + i0 + sg * 4;
    #pragma unroll 1
    for (int b = 0; b < 64; ++b) {
        const float4 gt = gsh[b];
        const int e0 = __float_as_int(gt.x), e1 = __float_as_int(gt.y);
        const float g0 = gt.z, g1 = gt.w;
        float4 G = *(const float4*)&T[0][fo];
        float4 X = *(const float4*)&T[1 + e0][fo];
        float4 Y = *(const float4*)&T[1 + e1][fo];
        short4v r;
        r[0] = (short)f2bf(G.x + g0 * X.x + g1 * Y.x);
        r[1] = (short)f2bf(G.y + g0 * X.y + g1 * Y.y);
        r[2] = (short)f2bf(G.z + g0 * X.z + g1 * Y.z);
        r[3] = (short)f2bf(G.w + g0 * X.w + g1 * Y.w);
        *(short4v*)(wrow + (size_t)b * 512 * 928) = r;
    }
}

// ---------------- Main fused batched GEMM: out[b] = x[b] @ Wcomb_b + bias ------
// Tile 64m x 512n per block, 8 waves, BK=32, 16x16x32 bf16 MFMA. grid (64 b, 8 m):
// lin%8 = b%8 -> battery b's blocks share one XCD (wcomb_b L2-resident).
//
// R3: counted-vmcnt raw-barrier pipeline (T4). __syncthreads drains vmcnt(0),
// capping prefetch depth at 1; replaced by a single-asm
//   s_waitcnt vmcnt(1) lgkmcnt(0); s_barrier
// so the A-register load (HBM x, ~900cy) rides TWO steps ahead across barriers,
// while the 4 B global_load_lds (issued first -> the 4 oldest; vmcnt(1) retires
// exactly them, in-order per m135) are drained with a full compute phase of
// cover. Issue order B-then-A is pinned with sched_barrier(0) (correctness-
// critical for the count). Tail steps peeled with exact vmcnt values.
__global__ __launch_bounds__(512, 4) void moe_gemm(const float* __restrict__ x,
                                                   const unsigned short* __restrict__ wc,
                                                   const float4* __restrict__ gates,
                                                   const float* __restrict__ eb,
                                                   const float* __restrict__ genb,
                                                   float* __restrict__ out) {
    __shared__ unsigned short As[2][64 * 40];    // [m][k] bf16, padded stride 40
    __shared__ unsigned short Bs[2][512 * 32];   // [n][k] bf16, slot-swizzled
    const int b  = blockIdx.x;
    const int m0 = blockIdx.y * 64;
    const int t = threadIdx.x, lane = t & 63, wid = t >> 6;
    const float4 gt = gates[b];
    const int e0 = __float_as_int(gt.x), e1 = __float_as_int(gt.y);
    const float g0 = gt.z, g1 = gt.w;
    const float* xb = x + (size_t)b * 512 * 900;
    const unsigned short* wcb = wc + (size_t)b * 512 * 928;
    f32x4 acc[4][4];
    #pragma unroll
    for (int mi = 0; mi < 4; ++mi)
        #pragma unroll
        for (int ni = 0; ni < 4; ++ni)
            acc[mi][ni] = (f32x4){0.f, 0.f, 0.f, 0.f};

    const int arow  = t >> 3;
    const int akoff = (t & 7) * 4;
    const float* xrow = xb + (size_t)(m0 + arow) * 900 + akoff;
    const int bseg = (lane & 3) ^ ((lane >> 3) & 3);
    const int burow = lane >> 2;

    const int wn = wid * 64;
    const int lm = lane & 15, lq = lane >> 4;

    auto loadA = [&](int kt) -> float4 {
        if (kt < 28) return *(const float4*)(xrow + kt * 32);
        float4 z = make_float4(0.f, 0.f, 0.f, 0.f);
        if (akoff == 0) z = *(const float4*)(xrow + 896);
        return z;
    };
    auto stageB = [&](int buf, int kt) {
        const int k0 = kt * 32;
        #pragma unroll
        for (int r = 0; r < 4; ++r) {
            const int chunk = wid * 4 + r;
            const int n = chunk * 16 + burow;
            const unsigned short* gsrc = wcb + (size_t)n * 928 + k0 + bseg * 8;
            unsigned short* ldst = &Bs[buf][chunk * 512];
            __builtin_amdgcn_global_load_lds(
                (const __attribute__((address_space(1))) unsigned int*)gsrc,
                (__attribute__((address_space(3))) unsigned int*)ldst, 16, 0, 0);
        }
    };
    auto packA = [&](int buf, float4 f) {
        *(short4v*)&As[buf][arow * 40 + akoff] = pk4(f);
    };
    auto compute = [&](int buf) {
        short8 af[4], bfr[4];
        #pragma unroll
        for (int mi = 0; mi < 4; ++mi)
            af[mi] = *(const short8*)&As[buf][(mi * 16 + lm) * 40 + lq * 8];
        #pragma unroll
        for (int ni = 0; ni < 4; ++ni) {
            const int n = wn + ni * 16 + lm;
            const int slot = lq ^ ((lm >> 1) & 3);
            bfr[ni] = *(const short8*)&Bs[buf][n * 32 + slot * 8];
        }
        #pragma unroll
        for (int mi = 0; mi < 4; ++mi)
            #pragma unroll
            for (int ni = 0; ni < 4; ++ni)
                acc[mi][ni] = __builtin_amdgcn_mfma_f32_16x16x32_bf16(
                    af[mi], bfr[ni], acc[mi][ni], 0, 0, 0);
    };

#define BAR_V1() do { \
    asm volatile("s_waitcnt vmcnt(1) lgkmcnt(0)\n\ts_barrier" ::: "memory"); \
    __builtin_amdgcn_sched_barrier(0); } while (0)
#define BAR_V0() do { \
    asm volatile("s_waitcnt vmcnt(0) lgkmcnt(0)\n\ts_barrier" ::: "memory"); \
    __builtin_amdgcn_sched_barrier(0); } while (0)

    // ---- prologue: stage kt=0 into buf 0; A_1 prefetched, left in flight
    stageB(0, 0);
    __builtin_amdgcn_sched_barrier(0);
    float4 a_cur  = loadA(0);
    float4 a_next = loadA(1);
    packA(0, a_cur);            // compiler wait for a_cur drains B0 too (prologue only)
    BAR_V1();                   // leaves a_next (A_1) outstanding

    // ---- steady state: t = 0..25 (13 pairs). Per step: B(t+1) then A(t+2),
    // compute(t), pack A(t+1), barrier vmcnt(1) (keeps A(t+2) in flight).
    #pragma unroll 1
    for (int p = 0; p < 13; ++p) {
        {   // t = 2p (buf 0)
            stageB(1, 2 * p + 1);
            __builtin_amdgcn_sched_barrier(0);
            float4 a2 = loadA(2 * p + 2);
            __builtin_amdgcn_sched_barrier(0);
            compute(0);
            packA(1, a_next);
            a_next = a2;
            BAR_V1();
        }
        {   // t = 2p+1 (buf 1)
            stageB(0, 2 * p + 2);
            __builtin_amdgcn_sched_barrier(0);
            float4 a2 = loadA(2 * p + 3);
            __builtin_amdgcn_sched_barrier(0);
            compute(1);
            packA(0, a_next);
            a_next = a2;
            BAR_V1();
        }
    }
    // ---- t = 26 (buf 0): last A prefetch (A_28)
    {
        stageB(1, 27);
        __builtin_amdgcn_sched_barrier(0);
        float4 a2 = loadA(28);
        __builtin_amdgcn_sched_barrier(0);
        compute(0);
        packA(1, a_next);
        a_next = a2;
        BAR_V1();
    }
    // ---- t = 27 (buf 1): no new A; full drain so B(28) is guaranteed landed
    {
        stageB(0, 28);
        __builtin_amdgcn_sched_barrier(0);
        compute(1);
        packA(0, a_next);
        BAR_V0();
    }
    // ---- t = 28 (buf 0): compute only
    compute(0);

#undef BAR_V1
#undef BAR_V0

    // ---- Epilogue: add gen_b + g0*eb[e0] + g1*eb[e1], store f32
    #pragma unroll
    for (int ni = 0; ni < 4; ++ni) {
        const int col = wn + ni * 16 + lm;
        const float bias = genb[col] + g0 * eb[e0 * 512 + col] + g1 * eb[e1 * 512 + col];
        #pragma unroll
        for (int mi = 0; mi < 4; ++mi) {
            const int row = m0 + mi * 16 + lq * 4;
            #pragma unroll
            for (int r = 0; r < 4; ++r)
                out[((size_t)b * 512 + row + r) * 512 + col] = acc[mi][ni][r] + bias;
        }
    }
}

extern "C" void kernel_launch(void* const* d_in, const int* in_sizes, int n_in,
                              void* d_out, int out_size, void* d_ws, size_t ws_size,
                              hipStream_t stream) {
    const float* x    = (const float*)d_in[0];   // [64][512][900]
    const float* cyc  = (const float*)d_in[1];   // [64][1]
    const float* dkp  = (const float*)d_in[2];   // [64][4096]
    const float* gW1  = (const float*)d_in[3];   // [4097][2048]
    const float* gb1  = (const float*)d_in[4];   // [2048]
    const float* gW2  = (const float*)d_in[5];   // [2048][8]
    const float* gb2  = (const float*)d_in[6];   // [8]
    const float* eW   = (const float*)d_in[7];   // [8][900][512]
    const float* eb   = (const float*)d_in[8];   // [8][512]
    const float* genW = (const float*)d_in[9];   // [900][512]
    const float* genb = (const float*)d_in[10];  // [512]
    float* out = (float*)d_out;                  // [64][512][512] f32

    char* ws = (char*)d_ws;
    // ws layout: [0, 60817408): Wcomb bf16 [64][512][928]; partials (8.4 MB,
    // [16][64][2048] f32) alias this region (dead before combine_w). gates after.
    unsigned short* wcomb = (unsigned short*)ws;
    float* part  = (float*)ws;
    float4* gts  = (float4*)(ws + 60817408);   // [64] {e0,e1,g0,g1}

    router1<<<dim3(16, 32), 256, 0, stream>>>(dkp, gW1, part);
    router23<<<64, 256, 0, stream>>>(part, cyc, gW1, gb1, gW2, gb2, gts);
    combine_w<<<dim3(16, 29), 256, 0, stream>>>(genW, eW, gts, wcomb);
    moe_gemm<<<dim3(64, 8), 512, 0, stream>>>(x, wcomb, gts, eb, genb, out);
}

// Round 3
// 335.176 us; speedup vs baseline: 1.1924x; 1.0844x over previous
//
#include <hip/hip_runtime.h>
#include <hip/hip_bf16.h>
#include <stdint.h>

typedef __attribute__((ext_vector_type(8))) short short8;
typedef __attribute__((ext_vector_type(4))) short short4v;
typedef __attribute__((ext_vector_type(4))) float f32x4;

__device__ inline unsigned short f2bf(float f) {
    union { float f; uint32_t u; } v; v.f = f;
    uint32_t u = v.u;
    uint32_t r = (u + 0x7FFFu + ((u >> 16) & 1u)) >> 16;   // RNE
    return (unsigned short)r;
}

__device__ inline short4v pk4(float4 a) {
    short4v r;
    r[0] = (short)f2bf(a.x); r[1] = (short)f2bf(a.y);
    r[2] = (short)f2bf(a.z); r[3] = (short)f2bf(a.w);
    return r;
}

// ---------------- Router kernel 1: partial GEMM  h_pre = g_in @ W1 -------------
// k-split 16, j-split 8 -> 512 blocks (2/CU). XCD grouping: lin%8 = jc so the 4
// bg-siblings sharing a W1 [256k x 256j] slice land on one XCD (L2 hit after
// first touch). R3: software-pipelined W1 loads (wcur/wnxt) — next oct's 8
// loads issue before current oct's FMAs, giving one full oct (~350 cy) of cover.
__global__ __launch_bounds__(256) void router1(const float* __restrict__ DKP,
                                               const float* __restrict__ W1,
                                               float* __restrict__ part) {
    __shared__ float gin[16 * 256];   // 16 KB
    const int t   = threadIdx.x;
    const int lin = blockIdx.x + 16 * blockIdx.y;   // grid (16,32) -> 0..511
    const int jc  = lin & 7;
    const int bg  = (lin >> 3) & 3;
    const int ks  = lin >> 5;                        // 0..15
    const int k0  = ks * 256;
    {   // stage g_in chunk [16 b][256 k]
        const int b = t >> 4, q = t & 15;
        #pragma unroll
        for (int s = 0; s < 4; ++s)
            *(float4*)(gin + b * 256 + q * 16 + s * 4) =
                *(const float4*)(DKP + (size_t)(bg * 16 + b) * 4096 + k0 + q * 16 + s * 4);
    }
    __syncthreads();
    const int ja = jc * 256 + t;
    float accA[16];
    #pragma unroll
    for (int b = 0; b < 16; ++b) accA[b] = 0.f;
    float wcur[8], wnxt[8];
    #pragma unroll
    for (int i = 0; i < 8; ++i)
        wcur[i] = W1[(size_t)(k0 + i) * 2048 + ja];
    #pragma unroll 2
    for (int oct = 0; oct < 32; ++oct) {
        const int kk = oct * 8;
        if (oct < 31) {
            #pragma unroll
            for (int i = 0; i < 8; ++i)
                wnxt[i] = W1[(size_t)(k0 + kk + 8 + i) * 2048 + ja];
        }
        #pragma unroll
        for (int b = 0; b < 16; ++b) {
            float4 g0 = *(const float4*)(gin + b * 256 + kk);
            float4 g1 = *(const float4*)(gin + b * 256 + kk + 4);
            accA[b] += g0.x*wcur[0] + g0.y*wcur[1] + g0.z*wcur[2] + g0.w*wcur[3]
                     + g1.x*wcur[4] + g1.y*wcur[5] + g1.z*wcur[6] + g1.w*wcur[7];
        }
        #pragma unroll
        for (int i = 0; i < 8; ++i) wcur[i] = wnxt[i];
    }
    #pragma unroll 1
    for (int b = 0; b < 16; ++b)
        part[((size_t)(ks * 64 + bg * 16 + b)) * 2048 + ja] = accA[b];
}

// ---------------- Router 2 (parallel): reduce splits + GELU + partial logits --
// grid (64 b, 8 jc) = 512 blocks (was 64 -> 0.25 blk/CU latency-bound). Each
// block handles 256 j's, produces 8 partial expert logits -> plog[b][jc][e].
__global__ __launch_bounds__(256) void router2p(const float* __restrict__ part,
                                                const float* __restrict__ cyc,
                                                const float* __restrict__ W1,
                                                const float* __restrict__ b1,
                                                const float* __restrict__ W2,
                                                float* __restrict__ plog) {
    __shared__ float red[256 * 8];
    const int b = blockIdx.x, jc = blockIdx.y;
    const int t = threadIdx.x;
    const int j = jc * 256 + t;
    float s = 0.f;
    #pragma unroll
    for (int tt = 0; tt < 16; ++tt)
        s += part[((size_t)tt * 64 + b) * 2048 + j];
    s += cyc[b] * W1[(size_t)4096 * 2048 + j] + b1[j];
    // jax.nn.gelu default (tanh approximation)
    const float u  = s + 0.044715f * s * s * s;
    const float th = tanhf(0.7978845608028654f * u);
    const float hv = 0.5f * s * (1.0f + th);
    const float* w = W2 + (size_t)j * 8;
    #pragma unroll
    for (int e = 0; e < 8; ++e) red[t * 8 + e] = hv * w[e];
    __syncthreads();
    if (t < 8) {
        float acc = 0.f;
        for (int r = 0; r < 256; ++r) acc += red[r * 8 + t];
        plog[((size_t)b * 8 + jc) * 8 + t] = acc;
    }
}

// ---------------- Router 4: final logits + top-2 + softmax + renorm gates -----
// 1 block, 64 threads: thread b owns battery b end-to-end (no cross-lane).
__global__ __launch_bounds__(64) void router4(const float* __restrict__ plog,
                                              const float* __restrict__ b2,
                                              float4* __restrict__ gates) {
    const int b = threadIdx.x;
    float l[8];
    #pragma unroll
    for (int e = 0; e < 8; ++e) l[e] = b2[e];
    #pragma unroll
    for (int jc = 0; jc < 8; ++jc)
        #pragma unroll
        for (int e = 0; e < 8; ++e)
            l[e] += plog[((size_t)b * 8 + jc) * 8 + e];
    int e0 = 0;
    #pragma unroll
    for (int e = 1; e < 8; ++e) if (l[e] > l[e0]) e0 = e;
    int e1 = (e0 == 0) ? 1 : 0;
    #pragma unroll
    for (int e = 0; e < 8; ++e) if (e != e0 && l[e] > l[e1]) e1 = e;
    const float m = l[e0];
    float p[8], Z = 0.f;
    #pragma unroll
    for (int e = 0; e < 8; ++e) { p[e] = expf(l[e] - m); Z += p[e]; }
    const float pe0 = p[e0] / Z, pe1 = p[e1] / Z;
    const float s2 = pe0 + pe1 + 1e-9f;
    gates[b] = make_float4(__int_as_float(e0), __int_as_float(e1), pe0 / s2, pe1 / s2);
}

// ---------------- Combine weights: wc[b][d][i] = (genW + g0*We0 + g1*We1)^T bf16
// [32i x 32d] tiles; stage genW + all 8 expert tiles transposed in LDS once,
// loop batteries in-block. R3: 2 batteries/iter (thread split t>>7) with short8
// (16 B) stores -> half the loop iterations and store instructions.
__global__ __launch_bounds__(256) void combine_w(const float* __restrict__ genW,
                                                 const float* __restrict__ expW,
                                                 const float4* __restrict__ gates,
                                                 unsigned short* __restrict__ wc) {
    __shared__ float T[9][32 * 36];   // [src][d_loc][i_loc], pad 36
    __shared__ float4 gsh[64];
    const int t  = threadIdx.x;
    const int d0 = blockIdx.x * 32;
    const int i0 = blockIdx.y * 32;
    if (t < 64) gsh[t] = gates[t];
    {
        const int il = t >> 3, d4 = (t & 7) * 4;
        const int i = i0 + il;
        const bool valid = (i < 900);
        const size_t off = (size_t)i * 512 + d0 + d4;
        #pragma unroll
        for (int s = 0; s < 9; ++s) {
            const float* src = (s == 0) ? genW : (expW + (size_t)(s - 1) * 900 * 512);
            float4 v = valid ? *(const float4*)(src + off) : make_float4(0, 0, 0, 0);
            float* Td = &T[s][0];
            Td[(d4 + 0) * 36 + il] = v.x;
            Td[(d4 + 1) * 36 + il] = v.y;
            Td[(d4 + 2) * 36 + il] = v.z;
            Td[(d4 + 3) * 36 + il] = v.w;
        }
    }
    __syncthreads();
    const int bb = t >> 7;              // 0/1: which battery of the pair
    const int dl = (t >> 2) & 31;       // d-row
    const int sg = t & 3;               // i-segment (8 i each)
    const int fo = dl * 36 + sg * 8;
    unsigned short* wrow = wc + (size_t)(d0 + dl) * 928 + i0 + sg * 8;
    #pragma unroll 2
    for (int bp = 0; bp < 32; ++bp) {
        const int b = bp * 2 + bb;
        const float4 gt = gsh[b];
        const int e0 = __float_as_int(gt.x), e1 = __float_as_int(gt.y);
        const float g0 = gt.z, g1 = gt.w;
        float4 Ga = *(const float4*)&T[0][fo],      Gb = *(const float4*)&T[0][fo + 4];
        float4 Xa = *(const float4*)&T[1 + e0][fo], Xb = *(const float4*)&T[1 + e0][fo + 4];
        float4 Ya = *(const float4*)&T[1 + e1][fo], Yb = *(const float4*)&T[1 + e1][fo + 4];
        short8 r;
        r[0] = (short)f2bf(Ga.x + g0 * Xa.x + g1 * Ya.x);
        r[1] = (short)f2bf(Ga.y + g0 * Xa.y + g1 * Ya.y);
        r[2] = (short)f2bf(Ga.z + g0 * Xa.z + g1 * Ya.z);
        r[3] = (short)f2bf(Ga.w + g0 * Xa.w + g1 * Ya.w);
        r[4] = (short)f2bf(Gb.x + g0 * Xb.x + g1 * Yb.x);
        r[5] = (short)f2bf(Gb.y + g0 * Xb.y + g1 * Yb.y);
        r[6] = (short)f2bf(Gb.z + g0 * Xb.z + g1 * Yb.z);
        r[7] = (short)f2bf(Gb.w + g0 * Xb.w + g1 * Yb.w);
        *(short8*)(wrow + (size_t)b * 512 * 928) = r;
    }
}

// ---------------- Main fused batched GEMM: out[b] = x[b] @ Wcomb_b + bias ------
// Tile 64m x 512n, 8 waves, BK=32, 16x16x32 bf16 MFMA.
//
// R3: depth-3 counted-vmcnt pipeline (T3+T4). 4 B-buffers + 2 A-buffers
// (141 KB LDS, 1 block/CU). Per step t: issue A(t+2) + B(t+3), compute(t),
// pack A(t+1) (compiler wait drains B(t+1)+A(t+1) — issued 2-3 phases ago),
// then `s_waitcnt vmcnt(9); s_barrier`. B loads get ~3 compute phases of cover
// (> L3 latency); steady-state keeps 9 VMEM ops in flight across each barrier.
// vmcnt constants are set-membership based (in-order retirement) -> robust to
// intra-step scheduling; NO sched_barrier pinning (m141 lesson).
// Buffer hazard: stage(t+3) overwrites buf read at t-1, separated by
// barrier(t-1). Grid 512 1-D, decode b=(g&7)+8*(g>>6), m=(g>>3)&7: each XCD's
// 32 resident blocks = 4 batteries x 8 m -> wcomb working set 3.8 MB <= L2.
__global__ __launch_bounds__(512) void moe_gemm(const float* __restrict__ x,
                                                const unsigned short* __restrict__ wc,
                                                const float4* __restrict__ gates,
                                                const float* __restrict__ eb,
                                                const float* __restrict__ genb,
                                                float* __restrict__ out) {
    __shared__ unsigned short As[2][64 * 40];    // [m][k] bf16, padded stride 40
    __shared__ unsigned short Bs[4][512 * 32];   // [n][k] bf16, slot-swizzled
    const int g  = blockIdx.x;
    const int b  = (g & 7) + 8 * (g >> 6);
    const int m0 = ((g >> 3) & 7) * 64;
    const int t = threadIdx.x, lane = t & 63, wid = t >> 6;
    const float4 gt = gates[b];
    const int e0 = __float_as_int(gt.x), e1 = __float_as_int(gt.y);
    const float g0 = gt.z, g1 = gt.w;
    const float* xb = x + (size_t)b * 512 * 900;
    const unsigned short* wcb = wc + (size_t)b * 512 * 928;
    f32x4 acc[4][4];
    #pragma unroll
    for (int mi = 0; mi < 4; ++mi)
        #pragma unroll
        for (int ni = 0; ni < 4; ++ni)
            acc[mi][ni] = (f32x4){0.f, 0.f, 0.f, 0.f};

    const int arow  = t >> 3;
    const int akoff = (t & 7) * 4;
    const float* xrow = xb + (size_t)(m0 + arow) * 900 + akoff;
    const int bseg = (lane & 3) ^ ((lane >> 3) & 3);
    const int burow = lane >> 2;

    const int wn = wid * 64;
    const int lm = lane & 15, lq = lane >> 4;

    auto loadA = [&](int kt) -> float4 {
        if (kt < 28) return *(const float4*)(xrow + kt * 32);
        // tail: only akoff==0 lanes have valid k (896..899); branchless so the
        // load instruction always issues (keeps vmcnt bookkeeping exact).
        const float* p = xrow + 896 - (akoff ? 32 : 0);
        float4 raw = *(const float4*)p;
        if (akoff) raw = make_float4(0.f, 0.f, 0.f, 0.f);
        return raw;
    };
    auto stageB = [&](int buf, int kt) {
        const int k0 = kt * 32;
        #pragma unroll
        for (int r = 0; r < 4; ++r) {
            const int chunk = wid * 4 + r;
            const int n = chunk * 16 + burow;
            const unsigned short* gsrc = wcb + (size_t)n * 928 + k0 + bseg * 8;
            unsigned short* ldst = &Bs[buf][chunk * 512];
            __builtin_amdgcn_global_load_lds(
                (const __attribute__((address_space(1))) unsigned int*)gsrc,
                (__attribute__((address_space(3))) unsigned int*)ldst, 16, 0, 0);
        }
    };
    auto packA = [&](int buf, float4 f) {
        *(short4v*)&As[buf][arow * 40 + akoff] = pk4(f);
    };
    auto compute = [&](int buf) {
        short8 af[4], bfr[4];
        #pragma unroll
        for (int mi = 0; mi < 4; ++mi)
            af[mi] = *(const short8*)&As[buf & 1][(mi * 16 + lm) * 40 + lq * 8];
        #pragma unroll
        for (int ni = 0; ni < 4; ++ni) {
            const int n = wn + ni * 16 + lm;
            const int slot = lq ^ ((lm >> 1) & 3);
            bfr[ni] = *(const short8*)&Bs[buf][n * 32 + slot * 8];
        }
        #pragma unroll
        for (int mi = 0; mi < 4; ++mi)
            #pragma unroll
            for (int ni = 0; ni < 4; ++ni)
                acc[mi][ni] = __builtin_amdgcn_mfma_f32_16x16x32_bf16(
                    af[mi], bfr[ni], acc[mi][ni], 0, 0, 0);
    };

#define BARN(n) asm volatile("s_waitcnt vmcnt(" #n ") lgkmcnt(0)\n\ts_barrier" ::: "memory")

    float4 a_next;
    // ---- prologue: issue A0,B0,A1,B1,B2 (14 VMEM in flight); pack A0 (compiler
    // waits for A0 only); barrier drains B0, leaves {A1,B1x4,B2x4}=9 in flight.
    {
        float4 a0 = loadA(0);
        stageB(0, 0);
        a_next = loadA(1);
        stageB(1, 1);
        stageB(2, 2);
        packA(0, a0);
        BARN(9);
    }
    // ---- steady: t=0..23 (6x4, buffer indices compile-time). Invariant at each
    // BARN(9): 9 VMEM in flight = {A(t+2), B(t+2)x4, B(t+3)x4}.
    #pragma unroll 1
    for (int q = 0; q < 6; ++q) {
        const int tb = q * 4;
        { float4 a2 = loadA(tb + 2); stageB(3, tb + 3); compute(0); packA(1, a_next); a_next = a2; BARN(9); }
        { float4 a2 = loadA(tb + 3); stageB(0, tb + 4); compute(1); packA(0, a_next); a_next = a2; BARN(9); }
        { float4 a2 = loadA(tb + 4); stageB(1, tb + 5); compute(2); packA(1, a_next); a_next = a2; BARN(9); }
        { float4 a2 = loadA(tb + 5); stageB(2, tb + 6); compute(3); packA(0, a_next); a_next = a2; BARN(9); }
    }
    // ---- peel: t=24..28
    { float4 a2 = loadA(26); stageB(3, 27); compute(0); packA(1, a_next); a_next = a2; BARN(9); }
    { float4 a2 = loadA(27); stageB(0, 28); compute(1); packA(0, a_next); a_next = a2; BARN(9); }
    { float4 a2 = loadA(28); compute(2); packA(1, a_next); a_next = a2; BARN(5); }
    { compute(3); packA(0, a_next); BARN(0); }
    compute(0);

#undef BARN

    // ---- Epilogue: add gen_b + g0*eb[e0] + g1*eb[e1], store f32
    #pragma unroll
    for (int ni = 0; ni < 4; ++ni) {
        const int col = wn + ni * 16 + lm;
        const float bias = genb[col] + g0 * eb[e0 * 512 + col] + g1 * eb[e1 * 512 + col];
        #pragma unroll
        for (int mi = 0; mi < 4; ++mi) {
            const int row = m0 + mi * 16 + lq * 4;
            #pragma unroll
            for (int r = 0; r < 4; ++r)
                out[((size_t)b * 512 + row + r) * 512 + col] = acc[mi][ni][r] + bias;
        }
    }
}

extern "C" void kernel_launch(void* const* d_in, const int* in_sizes, int n_in,
                              void* d_out, int out_size, void* d_ws, size_t ws_size,
                              hipStream_t stream) {
    const float* x    = (const float*)d_in[0];   // [64][512][900]
    const float* cyc  = (const float*)d_in[1];   // [64][1]
    const float* dkp  = (const float*)d_in[2];   // [64][4096]
    const float* gW1  = (const float*)d_in[3];   // [4097][2048]
    const float* gb1  = (const float*)d_in[4];   // [2048]
    const float* gW2  = (const float*)d_in[5];   // [2048][8]
    const float* gb2  = (const float*)d_in[6];   // [8]
    const float* eW   = (const float*)d_in[7];   // [8][900][512]
    const float* eb   = (const float*)d_in[8];   // [8][512]
    const float* genW = (const float*)d_in[9];   // [900][512]
    const float* genb = (const float*)d_in[10];  // [512]
    float* out = (float*)d_out;                  // [64][512][512] f32

    char* ws = (char*)d_ws;
    // ws layout: [0, 60817408): Wcomb bf16 [64][512][928]; partials (8.4 MB,
    // [16][64][2048] f32) alias this region (dead before combine_w).
    // Then gates (1 KB), plog (16 KB).
    unsigned short* wcomb = (unsigned short*)ws;
    float* part  = (float*)ws;
    float4* gts  = (float4*)(ws + 60817408);            // [64] {e0,e1,g0,g1}
    float* plog  = (float*)(ws + 60817408 + 1024);      // [64][8][8]

    router1<<<dim3(16, 32), 256, 0, stream>>>(dkp, gW1, part);
    router2p<<<dim3(64, 8), 256, 0, stream>>>(part, cyc, gW1, gb1, gW2, plog);
    router4<<<1, 64, 0, stream>>>(plog, gb2, gts);
    combine_w<<<dim3(16, 29), 256, 0, stream>>>(genW, eW, gts, wcomb);
    moe_gemm<<<512, 512, 0, stream>>>(x, wcomb, gts, eb, genb, out);
}

// Round 4
// 324.038 us; speedup vs baseline: 1.2334x; 1.0344x over previous
//
#include <hip/hip_runtime.h>
#include <hip/hip_bf16.h>
#include <stdint.h>

typedef __attribute__((ext_vector_type(8))) short short8;
typedef __attribute__((ext_vector_type(4))) short short4v;
typedef __attribute__((ext_vector_type(4))) float f32x4;

__device__ inline unsigned short f2bf(float f) {
    union { float f; uint32_t u; } v; v.f = f;
    uint32_t u = v.u;
    uint32_t r = (u + 0x7FFFu + ((u >> 16) & 1u)) >> 16;   // RNE
    return (unsigned short)r;
}

__device__ inline short8 pk8(float4 a, float4 b) {
    short8 r;
    r[0] = (short)f2bf(a.x); r[1] = (short)f2bf(a.y);
    r[2] = (short)f2bf(a.z); r[3] = (short)f2bf(a.w);
    r[4] = (short)f2bf(b.x); r[5] = (short)f2bf(b.y);
    r[6] = (short)f2bf(b.z); r[7] = (short)f2bf(b.w);
    return r;
}

// ---------------- Router kernel 1: partial GEMM  h_pre = g_in @ W1 -------------
// R4: was LDS-bound (1 j/thread -> 32 ds_read_b128 per 128 FMAs ~= 80 us).
// Now 4 j/thread (acc[16] x f32x4): 32 LDS reads per 512 FMAs -> FMA-bound
// (~7 us of v_fma work chip-wide). W1 loads are per-thread float4 (coalesced),
// software-pipelined one oct ahead. k-split 64 -> 512 blocks (2/CU).
// Decode bits: [0]=jc, [1:2]=ks-low, [3:4]=bg, [5:8]=ks-high. The 4 bg-siblings
// sharing a W1 slice have equal g%8 -> same XCD -> L2 hit after first touch.
__global__ __launch_bounds__(256) void router1(const float* __restrict__ DKP,
                                               const float* __restrict__ W1,
                                               float* __restrict__ part) {
    __shared__ float gin[16 * 64];   // 4 KB
    const int t  = threadIdx.x;
    const int g  = blockIdx.x;                        // 0..511
    const int jc = g & 1;
    const int bg = (g >> 3) & 3;
    const int ks = ((g >> 1) & 3) | ((g >> 5) << 2);  // 0..63
    const int k0 = ks * 64;
    {   // stage g_in chunk [16 b][64 k]
        const int bl = t >> 4, q = t & 15;
        *(float4*)(gin + bl * 64 + q * 4) =
            *(const float4*)(DKP + (size_t)(bg * 16 + bl) * 4096 + k0 + q * 4);
    }
    __syncthreads();
    const int ja = jc * 1024 + t * 4;   // 4 contiguous j per thread
    f32x4 acc[16];
    #pragma unroll
    for (int bl = 0; bl < 16; ++bl) acc[bl] = (f32x4){0.f, 0.f, 0.f, 0.f};
    f32x4 wcur[8], wnxt[8];
    #pragma unroll
    for (int i = 0; i < 8; ++i)
        wcur[i] = *(const f32x4*)(W1 + (size_t)(k0 + i) * 2048 + ja);
    #pragma unroll 1
    for (int oct = 0; oct < 8; ++oct) {
        const int kk = oct * 8;
        if (oct < 7) {
            #pragma unroll
            for (int i = 0; i < 8; ++i)
                wnxt[i] = *(const f32x4*)(W1 + (size_t)(k0 + kk + 8 + i) * 2048 + ja);
        }
        #pragma unroll
        for (int bl = 0; bl < 16; ++bl) {
            float4 g0 = *(const float4*)(gin + bl * 64 + kk);
            float4 g1 = *(const float4*)(gin + bl * 64 + kk + 4);
            f32x4 a = acc[bl];
            a = a + wcur[0] * g0.x + wcur[1] * g0.y + wcur[2] * g0.z + wcur[3] * g0.w
                  + wcur[4] * g1.x + wcur[5] * g1.y + wcur[6] * g1.z + wcur[7] * g1.w;
            acc[bl] = a;
        }
        #pragma unroll
        for (int i = 0; i < 8; ++i) wcur[i] = wnxt[i];
    }
    #pragma unroll 1
    for (int bl = 0; bl < 16; ++bl)
        *(f32x4*)(part + ((size_t)(ks * 64 + bg * 16 + bl)) * 2048 + ja) = acc[bl];
}

// ---------------- Router 2 (parallel): reduce splits + GELU + partial logits --
// grid (64 b, 8 jc). Reduces the 64 k-splits, applies bias+GELU, multiplies by
// W2 -> 8 partial expert logits per (b, jc) chunk.
__global__ __launch_bounds__(256) void router2p(const float* __restrict__ part,
                                                const float* __restrict__ cyc,
                                                const float* __restrict__ W1,
                                                const float* __restrict__ b1,
                                                const float* __restrict__ W2,
                                                float* __restrict__ plog) {
    __shared__ float red[256 * 8];
    const int b = blockIdx.x, jc = blockIdx.y;
    const int t = threadIdx.x;
    const int j = jc * 256 + t;
    float s = 0.f;
    #pragma unroll 8
    for (int tt = 0; tt < 64; ++tt)
        s += part[((size_t)tt * 64 + b) * 2048 + j];
    s += cyc[b] * W1[(size_t)4096 * 2048 + j] + b1[j];
    // jax.nn.gelu default (tanh approximation)
    const float u  = s + 0.044715f * s * s * s;
    const float th = tanhf(0.7978845608028654f * u);
    const float hv = 0.5f * s * (1.0f + th);
    const float* w = W2 + (size_t)j * 8;
    #pragma unroll
    for (int e = 0; e < 8; ++e) red[t * 8 + e] = hv * w[e];
    __syncthreads();
    if (t < 8) {
        float acc = 0.f;
        for (int r = 0; r < 256; ++r) acc += red[r * 8 + t];
        plog[((size_t)b * 8 + jc) * 8 + t] = acc;
    }
}

// ---------------- Router 4: final logits + top-2 + softmax + renorm gates -----
__global__ __launch_bounds__(64) void router4(const float* __restrict__ plog,
                                              const float* __restrict__ b2,
                                              float4* __restrict__ gates) {
    const int b = threadIdx.x;
    float l[8];
    #pragma unroll
    for (int e = 0; e < 8; ++e) l[e] = b2[e];
    #pragma unroll
    for (int jc = 0; jc < 8; ++jc)
        #pragma unroll
        for (int e = 0; e < 8; ++e)
            l[e] += plog[((size_t)b * 8 + jc) * 8 + e];
    int e0 = 0;
    #pragma unroll
    for (int e = 1; e < 8; ++e) if (l[e] > l[e0]) e0 = e;
    int e1 = (e0 == 0) ? 1 : 0;
    #pragma unroll
    for (int e = 0; e < 8; ++e) if (e != e0 && l[e] > l[e1]) e1 = e;
    const float m = l[e0];
    float p[8], Z = 0.f;
    #pragma unroll
    for (int e = 0; e < 8; ++e) { p[e] = expf(l[e] - m); Z += p[e]; }
    const float pe0 = p[e0] / Z, pe1 = p[e1] / Z;
    const float s2 = pe0 + pe1 + 1e-9f;
    gates[b] = make_float4(__int_as_float(e0), __int_as_float(e1), pe0 / s2, pe1 / s2);
}

// ---------------- Combine weights -> k-tiled layout --------------------------
// wc[b][kt][n][ksub]: [64][29][512][32] bf16 — each GEMM k-step's B-tile is one
// CONTIGUOUS 32 KB slab (R3 layout scattered 64 B segments 1856 B apart ->
// wasted half of every fetched line). [32i x 32d] tiles; stage genW + all 8
// expert tiles transposed in LDS once, loop the 64 batteries in-block.
// blockIdx.y IS kt. i >= 900 zero-padded (29*32 = 928).
__global__ __launch_bounds__(256) void combine_w(const float* __restrict__ genW,
                                                 const float* __restrict__ expW,
                                                 const float4* __restrict__ gates,
                                                 unsigned short* __restrict__ wc) {
    __shared__ float T[9][32 * 36];   // [src][d_loc][i_loc], pad 36 (conflict-free b128)
    __shared__ float4 gsh[64];
    const int t  = threadIdx.x;
    const int d0 = blockIdx.x * 32;
    const int kt = blockIdx.y;
    const int i0 = kt * 32;
    if (t < 64) gsh[t] = gates[t];
    {
        const int il = t >> 3, d4 = (t & 7) * 4;
        const int i = i0 + il;
        const bool valid = (i < 900);
        const size_t off = (size_t)i * 512 + d0 + d4;
        #pragma unroll
        for (int s = 0; s < 9; ++s) {
            const float* src = (s == 0) ? genW : (expW + (size_t)(s - 1) * 900 * 512);
            float4 v = valid ? *(const float4*)(src + off) : make_float4(0, 0, 0, 0);
            float* Td = &T[s][0];
            Td[(d4 + 0) * 36 + il] = v.x;
            Td[(d4 + 1) * 36 + il] = v.y;
            Td[(d4 + 2) * 36 + il] = v.z;
            Td[(d4 + 3) * 36 + il] = v.w;
        }
    }
    __syncthreads();
    const int bb = t >> 7;              // 0/1: which battery of the pair
    const int dl = (t >> 2) & 31;       // n-row (d_model dim)
    const int sg = t & 3;               // i-segment (8 i each)
    const int fo = dl * 36 + sg * 8;
    // new layout: b*475136 + kt*16384 + n*32 + ksub
    unsigned short* wrow = wc + (size_t)kt * 16384 + (d0 + dl) * 32 + sg * 8;
    #pragma unroll 2
    for (int bp = 0; bp < 32; ++bp) {
        const int b = bp * 2 + bb;
        const float4 gt = gsh[b];
        const int e0 = __float_as_int(gt.x), e1 = __float_as_int(gt.y);
        const float g0 = gt.z, g1 = gt.w;
        float4 Ga = *(const float4*)&T[0][fo],      Gb = *(const float4*)&T[0][fo + 4];
        float4 Xa = *(const float4*)&T[1 + e0][fo], Xb = *(const float4*)&T[1 + e0][fo + 4];
        float4 Ya = *(const float4*)&T[1 + e1][fo], Yb = *(const float4*)&T[1 + e1][fo + 4];
        short8 r;
        r[0] = (short)f2bf(Ga.x + g0 * Xa.x + g1 * Ya.x);
        r[1] = (short)f2bf(Ga.y + g0 * Xa.y + g1 * Ya.y);
        r[2] = (short)f2bf(Ga.z + g0 * Xa.z + g1 * Ya.z);
        r[3] = (short)f2bf(Ga.w + g0 * Xa.w + g1 * Ya.w);
        r[4] = (short)f2bf(Gb.x + g0 * Xb.x + g1 * Yb.x);
        r[5] = (short)f2bf(Gb.y + g0 * Xb.y + g1 * Yb.y);
        r[6] = (short)f2bf(Gb.z + g0 * Xb.z + g1 * Yb.z);
        r[7] = (short)f2bf(Gb.w + g0 * Xb.w + g1 * Yb.w);
        *(short8*)(wrow + (size_t)b * 475136) = r;
    }
}

// ---------------- Main fused batched GEMM: out[b] = x[b] @ Wcomb_b + bias ------
// R4: BM=128 (was 64) — the kernel is VMEM-TRAFFIC-bound (R0-R3 all ran at the
// ~10 B/cy/CU streaming ceiling regardless of pipeline depth). BM=128 halves
// the wcomb re-read factor (8x -> 4x): 670 -> 428 MB total. 8 waves as 2m x 4n,
// wave tile 64m x 128n, acc[4][8] (128 VGPR). BK=32, 16x16x32 bf16 MFMA.
// B-tile per k-step is one contiguous 32 KB slab (new wcomb layout) — full
// line utilization; lane sources pre-swizzled so LDS image keeps the slot-XOR
// (conflict-free ds_read_b128). Plain __syncthreads: in a traffic-bound regime
// the vmcnt(0) drain waits on bytes that must move anyway (R2/R3 evidence).
// grid 256 = 1 block/CU, single round; decode puts battery b's 4 m-siblings on
// one XCD, launched adjacently -> wcomb_b slab L2-resident for 3 of 4 reads.
__global__ __launch_bounds__(512, 1) void moe_gemm(const float* __restrict__ x,
                                                   const unsigned short* __restrict__ wc,
                                                   const float4* __restrict__ gates,
                                                   const float* __restrict__ eb,
                                                   const float* __restrict__ genb,
                                                   float* __restrict__ out) {
    __shared__ unsigned short As[2][128 * 40];   // [m][k] bf16, padded stride 40 (20 KB)
    __shared__ unsigned short Bs[2][512 * 32];   // [n][k] bf16, slot-swizzled   (64 KB)
    const int g  = blockIdx.x;
    const int b  = (g & 7) + 8 * (g >> 5);
    const int m0 = ((g >> 3) & 3) * 128;
    const int t = threadIdx.x, lane = t & 63, wid = t >> 6;
    const float4 gt = gates[b];
    const int e0 = __float_as_int(gt.x), e1 = __float_as_int(gt.y);
    const float g0 = gt.z, g1 = gt.w;
    const float* xb = x + (size_t)b * 512 * 900;
    const unsigned short* wcb = wc + (size_t)b * 475136;
    f32x4 acc[4][8];
    #pragma unroll
    for (int mi = 0; mi < 4; ++mi)
        #pragma unroll
        for (int ni = 0; ni < 8; ++ni)
            acc[mi][ni] = (f32x4){0.f, 0.f, 0.f, 0.f};

    // A staging: thread -> row t>>2 (128 rows), 8 floats at (t&3)*8
    const int arow = t >> 2;
    const int acol = (t & 3) * 8;
    const float* xrow = xb + (size_t)(m0 + arow) * 900 + acol;
    // B staging: lane -> row u=lane>>2 in 16-row chunk; slot=lane&3 holds
    // global seg = slot ^ ((u>>1)&3) = slot ^ ((lane>>3)&3)
    const int bseg  = (lane & 3) ^ ((lane >> 3) & 3);
    const int burow = lane >> 2;

    const int wm = wid >> 2;            // 0..1 : m-half
    const int wn = (wid & 3) * 128;     // n-origin of wave
    const int lm = lane & 15, lq = lane >> 4;

    auto stageB = [&](int buf, int kt) {
        const unsigned short* slab = wcb + (size_t)kt * 16384;
        #pragma unroll
        for (int r = 0; r < 4; ++r) {
            const int chunk = wid * 4 + r;
            const unsigned short* gsrc = slab + (chunk * 16 + burow) * 32 + bseg * 8;
            unsigned short* ldst = &Bs[buf][chunk * 512];
            __builtin_amdgcn_global_load_lds(
                (const __attribute__((address_space(1))) unsigned int*)gsrc,
                (__attribute__((address_space(3))) unsigned int*)ldst, 16, 0, 0);
        }
    };
    auto loadA = [&](int kt, float4& lo, float4& hi) {
        if (kt < 28) {
            lo = *(const float4*)(xrow + kt * 32);
            hi = *(const float4*)(xrow + kt * 32 + 4);
        } else {   // k = 896 + acol .. : valid only acol==0, floats 896..899
            lo = make_float4(0.f, 0.f, 0.f, 0.f);
            hi = make_float4(0.f, 0.f, 0.f, 0.f);
            if (acol == 0) lo = *(const float4*)(xb + (size_t)(m0 + arow) * 900 + 896);
        }
    };
    auto packA = [&](int buf, float4 lo, float4 hi) {
        *(short8*)&As[buf][arow * 40 + acol] = pk8(lo, hi);
    };
    auto compute = [&](int buf) {
        short8 af[4];
        #pragma unroll
        for (int mi = 0; mi < 4; ++mi)
            af[mi] = *(const short8*)&As[buf][(wm * 64 + mi * 16 + lm) * 40 + lq * 8];
        #pragma unroll
        for (int ni = 0; ni < 8; ++ni) {
            const int n = wn + ni * 16 + lm;
            const int slot = lq ^ ((lm >> 1) & 3);
            short8 bf = *(const short8*)&Bs[buf][n * 32 + slot * 8];
            #pragma unroll
            for (int mi = 0; mi < 4; ++mi)
                acc[mi][ni] = __builtin_amdgcn_mfma_f32_16x16x32_bf16(
                    af[mi], bf, acc[mi][ni], 0, 0, 0);
        }
    };

    // ---- prologue: stage kt=0 into buf 0
    {
        float4 lo, hi;
        loadA(0, lo, hi);
        stageB(0, 0);
        packA(0, lo, hi);
        __syncthreads();
    }
    // ---- main loop: 28 staging steps, hand-unrolled x2 for buffer constants.
    // Order per step: issue A(t+1) loads + B(t+1) global_load_lds, THEN
    // compute(t) (loads fly under ~1600 cy of MFMA+LDS), then pack A, barrier.
    #pragma unroll 1
    for (int p = 0; p < 14; ++p) {
        {
            float4 lo, hi;
            loadA(2 * p + 1, lo, hi);
            stageB(1, 2 * p + 1);
            compute(0);
            packA(1, lo, hi);
            __syncthreads();
        }
        {
            float4 lo, hi;
            loadA(2 * p + 2, lo, hi);
            stageB(0, 2 * p + 2);
            compute(1);
            packA(0, lo, hi);
            __syncthreads();
        }
    }
    // ---- final step kt=28 from buf 0
    compute(0);

    // ---- Epilogue: add gen_b + g0*eb[e0] + g1*eb[e1], store f32
    #pragma unroll
    for (int ni = 0; ni < 8; ++ni) {
        const int col = wn + ni * 16 + lm;
        const float bias = genb[col] + g0 * eb[e0 * 512 + col] + g1 * eb[e1 * 512 + col];
        #pragma unroll
        for (int mi = 0; mi < 4; ++mi) {
            const int row = m0 + wm * 64 + mi * 16 + lq * 4;
            #pragma unroll
            for (int r = 0; r < 4; ++r)
                out[((size_t)b * 512 + row + r) * 512 + col] = acc[mi][ni][r] + bias;
        }
    }
}

extern "C" void kernel_launch(void* const* d_in, const int* in_sizes, int n_in,
                              void* d_out, int out_size, void* d_ws, size_t ws_size,
                              hipStream_t stream) {
    const float* x    = (const float*)d_in[0];   // [64][512][900]
    const float* cyc  = (const float*)d_in[1];   // [64][1]
    const float* dkp  = (const float*)d_in[2];   // [64][4096]
    const float* gW1  = (const float*)d_in[3];   // [4097][2048]
    const float* gb1  = (const float*)d_in[4];   // [2048]
    const float* gW2  = (const float*)d_in[5];   // [2048][8]
    const float* gb2  = (const float*)d_in[6];   // [8]
    const float* eW   = (const float*)d_in[7];   // [8][900][512]
    const float* eb   = (const float*)d_in[8];   // [8][512]
    const float* genW = (const float*)d_in[9];   // [900][512]
    const float* genb = (const float*)d_in[10];  // [512]
    float* out = (float*)d_out;                  // [64][512][512] f32

    char* ws = (char*)d_ws;
    // ws layout: [0, 60817408): Wcomb bf16 [64][29][512][32] (k-tiled slabs);
    // partials ([64][64][2048] f32 = 33.5 MB) alias this region (dead before
    // combine_w runs). Then gates (1 KB), plog (16 KB).
    unsigned short* wcomb = (unsigned short*)ws;
    float* part  = (float*)ws;
    float4* gts  = (float4*)(ws + 60817408);            // [64] {e0,e1,g0,g1}
    float* plog  = (float*)(ws + 60817408 + 1024);      // [64][8][8]

    router1<<<512, 256, 0, stream>>>(dkp, gW1, part);
    router2p<<<dim3(64, 8), 256, 0, stream>>>(part, cyc, gW1, gb1, gW2, plog);
    router4<<<1, 64, 0, stream>>>(plog, gb2, gts);
    combine_w<<<dim3(16, 29), 256, 0, stream>>>(genW, eW, gts, wcomb);
    moe_gemm<<<256, 512, 0, stream>>>(x, wcomb, gts, eb, genb, out);
}